// Round 1
// baseline (2141.794 us; speedup 1.0000x reference)
//
#include <hip/hip_runtime.h>

#define N_NODES 100000
#define N_EDGES 3200000
#define IN_F 500
#define HID 64
#define OUT_F 64
#define ALPHA 0.1f
#define K_ITERS 10
#define SCAN_B ((N_NODES + 255) / 256)   // 391

// ---------------------------------------------------------------------------
// Fused MLP: h = relu(x@W1+b1)@W2+b2 ; ah = ALPHA*h
// Block = 256 threads = 4 waves; block handles 16 rows x 64 cols.
// wave rg handles rows rg*4..rg*4+3 (LDS broadcasts), lane = output col.
// ---------------------------------------------------------------------------
__global__ __launch_bounds__(256) void mlp_kernel(
    const float* __restrict__ x, const float* __restrict__ W1,
    const float* __restrict__ b1, const float* __restrict__ W2,
    const float* __restrict__ b2, float* __restrict__ h,
    float* __restrict__ ah)
{
    __shared__ float xs[16][100];   // 6.4 KB: chunk of 16 x-rows
    __shared__ float hid[16][64];   // 4 KB
    __shared__ float w2s[64][64];   // 16 KB

    const int tid = threadIdx.x;
    const int c   = tid & 63;
    const int rg  = tid >> 6;               // 0..3
    const int block_row = blockIdx.x * 16;  // 6250*16 == 100000 exactly

    float acc0 = 0.f, acc1 = 0.f, acc2 = 0.f, acc3 = 0.f;

    for (int kb = 0; kb < IN_F; kb += 100) {   // 500 = 5 * 100
        for (int i = tid; i < 16 * 100; i += 256) {
            int r = i / 100, cc = i - r * 100;
            xs[r][cc] = x[(long)(block_row + r) * IN_F + kb + cc];
        }
        __syncthreads();
        #pragma unroll 4
        for (int k = 0; k < 100; ++k) {
            float w = W1[(kb + k) * HID + c];   // coalesced, L1-hot
            acc0 = fmaf(xs[rg*4+0][k], w, acc0);
            acc1 = fmaf(xs[rg*4+1][k], w, acc1);
            acc2 = fmaf(xs[rg*4+2][k], w, acc2);
            acc3 = fmaf(xs[rg*4+3][k], w, acc3);
        }
        __syncthreads();
    }

    float b = b1[c];
    hid[rg*4+0][c] = fmaxf(acc0 + b, 0.f);
    hid[rg*4+1][c] = fmaxf(acc1 + b, 0.f);
    hid[rg*4+2][c] = fmaxf(acc2 + b, 0.f);
    hid[rg*4+3][c] = fmaxf(acc3 + b, 0.f);
    for (int i = tid; i < 64 * 64; i += 256) w2s[i >> 6][i & 63] = W2[i];
    __syncthreads();

    float o0 = 0.f, o1 = 0.f, o2 = 0.f, o3 = 0.f;
    #pragma unroll 8
    for (int k = 0; k < HID; ++k) {
        float w = w2s[k][c];
        o0 = fmaf(hid[rg*4+0][k], w, o0);
        o1 = fmaf(hid[rg*4+1][k], w, o1);
        o2 = fmaf(hid[rg*4+2][k], w, o2);
        o3 = fmaf(hid[rg*4+3][k], w, o3);
    }
    float bb = b2[c];
    int r0 = block_row + rg * 4;
    float v0 = o0 + bb, v1 = o1 + bb, v2 = o2 + bb, v3 = o3 + bb;
    h[(r0+0)*64 + c] = v0;  ah[(r0+0)*64 + c] = ALPHA * v0;
    h[(r0+1)*64 + c] = v1;  ah[(r0+1)*64 + c] = ALPHA * v1;
    h[(r0+2)*64 + c] = v2;  ah[(r0+2)*64 + c] = ALPHA * v2;
    h[(r0+3)*64 + c] = v3;  ah[(r0+3)*64 + c] = ALPHA * v3;
}

// ---------------------------------------------------------------------------
// CSR build: count -> 2-level exclusive scan -> atomic fill
// ---------------------------------------------------------------------------
__global__ __launch_bounds__(256) void zero_cnt(int* __restrict__ cnt)
{
    int i = blockIdx.x * 256 + threadIdx.x;
    if (i < N_NODES) cnt[i] = 0;
}

__global__ __launch_bounds__(256) void count_edges(
    const int* __restrict__ dst, int* __restrict__ cnt)
{
    int i = blockIdx.x * 256 + threadIdx.x;
    if (i < N_EDGES) atomicAdd(&cnt[dst[i]], 1);
}

__global__ __launch_bounds__(256) void scan_block_sums(
    const int* __restrict__ cnt, int* __restrict__ bsum)
{
    int i = blockIdx.x * 256 + threadIdx.x;
    int v = (i < N_NODES) ? cnt[i] : 0;
    for (int off = 32; off; off >>= 1) v += __shfl_down(v, off);
    __shared__ int ws_[4];
    if ((threadIdx.x & 63) == 0) ws_[threadIdx.x >> 6] = v;
    __syncthreads();
    if (threadIdx.x == 0) bsum[blockIdx.x] = ws_[0] + ws_[1] + ws_[2] + ws_[3];
}

__global__ __launch_bounds__(512) void scan_partials(
    const int* __restrict__ bsum, int* __restrict__ boff)
{
    int t = threadIdx.x;
    int v = (t < SCAN_B) ? bsum[t] : 0;
    int lane = t & 63, w = t >> 6;   // 8 waves
    int x = v;
    for (int off = 1; off < 64; off <<= 1) {
        int y = __shfl_up(x, off);
        if (lane >= off) x += y;
    }
    __shared__ int wsum[8];
    if (lane == 63) wsum[w] = x;
    __syncthreads();
    if (w == 0) {
        int s = (lane < 8) ? wsum[lane] : 0;
        for (int off = 1; off < 8; off <<= 1) {
            int y = __shfl_up(s, off);
            if (lane >= off) s += y;
        }
        if (lane < 8) wsum[lane] = s;   // inclusive wave sums
    }
    __syncthreads();
    int wpre = (w == 0) ? 0 : wsum[w - 1];
    if (t < SCAN_B) boff[t] = wpre + x - v;   // exclusive
}

__global__ __launch_bounds__(256) void scan_final(
    const int* __restrict__ cnt, const int* __restrict__ boff,
    int* __restrict__ row_start, int* __restrict__ pos)
{
    int i = blockIdx.x * 256 + threadIdx.x;
    int v = (i < N_NODES) ? cnt[i] : 0;
    int lane = threadIdx.x & 63, w = threadIdx.x >> 6;  // 4 waves
    int x = v;
    for (int off = 1; off < 64; off <<= 1) {
        int y = __shfl_up(x, off);
        if (lane >= off) x += y;
    }
    __shared__ int wsum[4];
    if (lane == 63) wsum[w] = x;
    __syncthreads();
    int wpre = 0;
    for (int ww = 0; ww < w; ++ww) wpre += wsum[ww];
    int excl = wpre + x - v;
    int r = boff[blockIdx.x] + excl;
    if (i < N_NODES) { row_start[i] = r; pos[i] = r; }
    if (i == 0) row_start[N_NODES] = N_EDGES;
}

__global__ __launch_bounds__(256) void fill_csr(
    const int* __restrict__ src, const int* __restrict__ dst,
    const float* __restrict__ w, int* __restrict__ pos,
    int* __restrict__ csr_src, float* __restrict__ csr_w)
{
    int i = blockIdx.x * 256 + threadIdx.x;
    if (i < N_EDGES) {
        int p = atomicAdd(&pos[dst[i]], 1);
        csr_src[p] = src[i];
        csr_w[p]   = 0.9f * w[i];   // fold (1-ALPHA) into edge weight
    }
}

// ---------------------------------------------------------------------------
// Pull-based SpMM: zout[d] = ah[d] + sum_j csr_w[j] * zin[csr_src[j]]
// One wave per dst node, lane = feature. No atomics. Unroll-4 for MLP.
// ---------------------------------------------------------------------------
__global__ __launch_bounds__(256) void spmm_kernel(
    const int* __restrict__ row_start, const int* __restrict__ csr_src,
    const float* __restrict__ csr_w, const float* __restrict__ zin,
    const float* __restrict__ ah, float* __restrict__ zout)
{
    const int node = blockIdx.x * 4 + (threadIdx.x >> 6);  // 25000*4 == 100000
    const int f = threadIdx.x & 63;
    const int s0 = row_start[node];
    const int s1 = row_start[node + 1];
    float acc = ah[node * 64 + f];
    int j = s0;
    for (; j + 4 <= s1; j += 4) {
        int a0 = csr_src[j],   a1 = csr_src[j+1];
        int a2 = csr_src[j+2], a3 = csr_src[j+3];
        float w0 = csr_w[j],   w1 = csr_w[j+1];
        float w2 = csr_w[j+2], w3 = csr_w[j+3];
        float v0 = zin[a0*64+f], v1 = zin[a1*64+f];
        float v2 = zin[a2*64+f], v3 = zin[a3*64+f];
        acc = fmaf(w0, v0, acc);
        acc = fmaf(w1, v1, acc);
        acc = fmaf(w2, v2, acc);
        acc = fmaf(w3, v3, acc);
    }
    for (; j < s1; ++j)
        acc = fmaf(csr_w[j], zin[csr_src[j]*64 + f], acc);
    zout[node * 64 + f] = acc;
}

// ---------------------------------------------------------------------------
extern "C" void kernel_launch(void* const* d_in, const int* in_sizes, int n_in,
                              void* d_out, int out_size, void* d_ws, size_t ws_size,
                              hipStream_t stream)
{
    const float* x    = (const float*)d_in[0];
    const int*   esrc = (const int*)d_in[1];
    const int*   edst = (const int*)d_in[2];
    const float* ew   = (const float*)d_in[3];
    const float* W1   = (const float*)d_in[4];
    const float* b1   = (const float*)d_in[5];
    const float* W2   = (const float*)d_in[6];
    const float* b2   = (const float*)d_in[7];
    float* out = (float*)d_out;

    // workspace layout (~104 MB)
    char* p = (char*)d_ws;
    float* h  = (float*)p;  p += (size_t)N_NODES * 64 * 4;
    float* ah = (float*)p;  p += (size_t)N_NODES * 64 * 4;
    float* zA = (float*)p;  p += (size_t)N_NODES * 64 * 4;
    int*   csr_src = (int*)p;    p += (size_t)N_EDGES * 4;
    float* csr_w   = (float*)p;  p += (size_t)N_EDGES * 4;
    int* cnt       = (int*)p;    p += (size_t)N_NODES * 4;
    int* pos       = (int*)p;    p += (size_t)N_NODES * 4;
    int* row_start = (int*)p;    p += (size_t)(N_NODES + 1) * 4;
    int* bsum      = (int*)p;    p += (size_t)SCAN_B * 4;
    int* boff      = (int*)p;    p += (size_t)SCAN_B * 4;

    const int EB = (N_EDGES + 255) / 256;

    hipLaunchKernelGGL(mlp_kernel, dim3(N_NODES / 16), dim3(256), 0, stream,
                       x, W1, b1, W2, b2, h, ah);
    hipLaunchKernelGGL(zero_cnt, dim3(SCAN_B), dim3(256), 0, stream, cnt);
    hipLaunchKernelGGL(count_edges, dim3(EB), dim3(256), 0, stream, edst, cnt);
    hipLaunchKernelGGL(scan_block_sums, dim3(SCAN_B), dim3(256), 0, stream, cnt, bsum);
    hipLaunchKernelGGL(scan_partials, dim3(1), dim3(512), 0, stream, bsum, boff);
    hipLaunchKernelGGL(scan_final, dim3(SCAN_B), dim3(256), 0, stream,
                       cnt, boff, row_start, pos);
    hipLaunchKernelGGL(fill_csr, dim3(EB), dim3(256), 0, stream,
                       esrc, edst, ew, pos, csr_src, csr_w);

    // Ping-pong: iter0 h->zA; odd iters ->out; even iters ->zA; iter9 ends in out.
    const float* zi = h;
    float* zo = zA;
    for (int it = 0; it < K_ITERS; ++it) {
        hipLaunchKernelGGL(spmm_kernel, dim3(N_NODES / 4), dim3(256), 0, stream,
                           row_start, csr_src, csr_w, zi, ah, zo);
        zi = zo;
        zo = (it % 2 == 0) ? out : zA;
    }
}

// Round 3
// 1876.536 us; speedup vs baseline: 1.1414x; 1.1414x over previous
//
#include <hip/hip_runtime.h>

#define N_NODES 100000
#define N_EDGES 3200000
#define IN_F 500
#define HID 64
#define OUT_F 64
#define ALPHA 0.1f
#define K_ITERS 10
#define SCAN_B ((N_NODES + 255) / 256)   // 391

typedef unsigned short ushort_t;
typedef unsigned int uint_t;

__device__ __forceinline__ float bf2f(ushort_t v) {
    union { uint_t u; float f; } c; c.u = ((uint_t)v) << 16; return c.f;
}
__device__ __forceinline__ ushort_t f2b(float f) {
    union { float f; uint_t u; } c; c.f = f;
    uint_t u = c.u + 0x7fffu + ((c.u >> 16) & 1u);   // round-to-nearest-even
    return (ushort_t)(u >> 16);
}

// ---------------------------------------------------------------------------
// Fused MLP: v = relu(x@W1+b1)@W2+b2 ; writes hb = bf16(v), ahb = bf16(ALPHA*v)
// Block = 256 = 4 waves; block does 16 rows x 64 cols; wave rg does rows rg*4..+3.
// Inner loop k-unrolled by 4 via float4 LDS reads: 16 FMA per 8 mem ops.
// ---------------------------------------------------------------------------
__global__ __launch_bounds__(256) void mlp_kernel(
    const float* __restrict__ x, const float* __restrict__ W1,
    const float* __restrict__ b1, const float* __restrict__ W2,
    const float* __restrict__ b2, ushort_t* __restrict__ hb,
    ushort_t* __restrict__ ahb)
{
    __shared__ float xs[16][100];   // 6.4 KB
    __shared__ float hid[16][64];   // 4 KB
    __shared__ float w2s[64][64];   // 16 KB

    const int tid = threadIdx.x;
    const int c   = tid & 63;
    const int rg  = tid >> 6;
    const int block_row = blockIdx.x * 16;   // 6250*16 == 100000

    float acc0 = 0.f, acc1 = 0.f, acc2 = 0.f, acc3 = 0.f;

    for (int kb = 0; kb < IN_F; kb += 100) {
        for (int i = tid; i < 400; i += 256) {
            int r = i / 25, c4 = i - r * 25;
            *(float4*)&xs[r][c4 * 4] =
                *(const float4*)&x[(long)(block_row + r) * IN_F + kb + c4 * 4];
        }
        __syncthreads();
        for (int k = 0; k < 100; k += 4) {
            float4 x0 = *(const float4*)&xs[rg*4+0][k];
            float4 x1 = *(const float4*)&xs[rg*4+1][k];
            float4 x2 = *(const float4*)&xs[rg*4+2][k];
            float4 x3 = *(const float4*)&xs[rg*4+3][k];
            float w0 = W1[(kb+k+0)*HID + c];
            float w1 = W1[(kb+k+1)*HID + c];
            float w2 = W1[(kb+k+2)*HID + c];
            float w3 = W1[(kb+k+3)*HID + c];
            acc0 = fmaf(x0.x, w0, acc0); acc1 = fmaf(x1.x, w0, acc1);
            acc2 = fmaf(x2.x, w0, acc2); acc3 = fmaf(x3.x, w0, acc3);
            acc0 = fmaf(x0.y, w1, acc0); acc1 = fmaf(x1.y, w1, acc1);
            acc2 = fmaf(x2.y, w1, acc2); acc3 = fmaf(x3.y, w1, acc3);
            acc0 = fmaf(x0.z, w2, acc0); acc1 = fmaf(x1.z, w2, acc1);
            acc2 = fmaf(x2.z, w2, acc2); acc3 = fmaf(x3.z, w2, acc3);
            acc0 = fmaf(x0.w, w3, acc0); acc1 = fmaf(x1.w, w3, acc1);
            acc2 = fmaf(x2.w, w3, acc2); acc3 = fmaf(x3.w, w3, acc3);
        }
        __syncthreads();
    }

    float b = b1[c];
    hid[rg*4+0][c] = fmaxf(acc0 + b, 0.f);
    hid[rg*4+1][c] = fmaxf(acc1 + b, 0.f);
    hid[rg*4+2][c] = fmaxf(acc2 + b, 0.f);
    hid[rg*4+3][c] = fmaxf(acc3 + b, 0.f);
    for (int i = tid; i < 64 * 64; i += 256) w2s[i >> 6][i & 63] = W2[i];
    __syncthreads();

    float o0 = 0.f, o1 = 0.f, o2 = 0.f, o3 = 0.f;
    for (int k = 0; k < HID; k += 4) {
        float4 h0 = *(const float4*)&hid[rg*4+0][k];
        float4 h1 = *(const float4*)&hid[rg*4+1][k];
        float4 h2 = *(const float4*)&hid[rg*4+2][k];
        float4 h3 = *(const float4*)&hid[rg*4+3][k];
        float w0 = w2s[k+0][c], w1 = w2s[k+1][c];
        float w2 = w2s[k+2][c], w3 = w2s[k+3][c];
        o0 = fmaf(h0.x, w0, o0); o1 = fmaf(h1.x, w0, o1);
        o2 = fmaf(h2.x, w0, o2); o3 = fmaf(h3.x, w0, o3);
        o0 = fmaf(h0.y, w1, o0); o1 = fmaf(h1.y, w1, o1);
        o2 = fmaf(h2.y, w1, o2); o3 = fmaf(h3.y, w1, o3);
        o0 = fmaf(h0.z, w2, o0); o1 = fmaf(h1.z, w2, o1);
        o2 = fmaf(h2.z, w2, o2); o3 = fmaf(h3.z, w2, o3);
        o0 = fmaf(h0.w, w3, o0); o1 = fmaf(h1.w, w3, o1);
        o2 = fmaf(h2.w, w3, o2); o3 = fmaf(h3.w, w3, o3);
    }
    float bb = b2[c];
    int r0 = block_row + rg * 4;
    float v0 = o0 + bb, v1 = o1 + bb, v2 = o2 + bb, v3 = o3 + bb;
    hb[(r0+0)*64 + c] = f2b(v0);  ahb[(r0+0)*64 + c] = f2b(ALPHA * v0);
    hb[(r0+1)*64 + c] = f2b(v1);  ahb[(r0+1)*64 + c] = f2b(ALPHA * v1);
    hb[(r0+2)*64 + c] = f2b(v2);  ahb[(r0+2)*64 + c] = f2b(ALPHA * v2);
    hb[(r0+3)*64 + c] = f2b(v3);  ahb[(r0+3)*64 + c] = f2b(ALPHA * v3);
}

// ---------------------------------------------------------------------------
// Counting-sort machinery (used twice: by src, then by dst)
// ---------------------------------------------------------------------------
__global__ __launch_bounds__(256) void zero_cnt(int* __restrict__ cnt)
{
    int i = blockIdx.x * 256 + threadIdx.x;
    if (i < N_NODES) cnt[i] = 0;
}

__global__ __launch_bounds__(256) void count_keys(
    const int* __restrict__ key, int* __restrict__ cnt)
{
    int i = blockIdx.x * 256 + threadIdx.x;
    if (i < N_EDGES) atomicAdd(&cnt[key[i]], 1);
}

__global__ __launch_bounds__(256) void scan_block_sums(
    const int* __restrict__ cnt, int* __restrict__ bsum)
{
    int i = blockIdx.x * 256 + threadIdx.x;
    int v = (i < N_NODES) ? cnt[i] : 0;
    for (int off = 32; off; off >>= 1) v += __shfl_down(v, off);
    __shared__ int ws_[4];
    if ((threadIdx.x & 63) == 0) ws_[threadIdx.x >> 6] = v;
    __syncthreads();
    if (threadIdx.x == 0) bsum[blockIdx.x] = ws_[0] + ws_[1] + ws_[2] + ws_[3];
}

__global__ __launch_bounds__(512) void scan_partials(
    const int* __restrict__ bsum, int* __restrict__ boff)
{
    int t = threadIdx.x;
    int v = (t < SCAN_B) ? bsum[t] : 0;
    int lane = t & 63, w = t >> 6;
    int x = v;
    for (int off = 1; off < 64; off <<= 1) {
        int y = __shfl_up(x, off);
        if (lane >= off) x += y;
    }
    __shared__ int wsum[8];
    if (lane == 63) wsum[w] = x;
    __syncthreads();
    if (w == 0) {
        int s = (lane < 8) ? wsum[lane] : 0;
        for (int off = 1; off < 8; off <<= 1) {
            int y = __shfl_up(s, off);
            if (lane >= off) s += y;
        }
        if (lane < 8) wsum[lane] = s;
    }
    __syncthreads();
    int wpre = (w == 0) ? 0 : wsum[w - 1];
    if (t < SCAN_B) boff[t] = wpre + x - v;
}

__global__ __launch_bounds__(256) void scan_final(
    const int* __restrict__ cnt, const int* __restrict__ boff,
    int* __restrict__ row_start, int* __restrict__ pos)
{
    int i = blockIdx.x * 256 + threadIdx.x;
    int v = (i < N_NODES) ? cnt[i] : 0;
    int lane = threadIdx.x & 63, w = threadIdx.x >> 6;
    int x = v;
    for (int off = 1; off < 64; off <<= 1) {
        int y = __shfl_up(x, off);
        if (lane >= off) x += y;
    }
    __shared__ int wsum[4];
    if (lane == 63) wsum[w] = x;
    __syncthreads();
    int wpre = 0;
    for (int ww = 0; ww < w; ++ww) wpre += wsum[ww];
    int excl = wpre + x - v;
    int r = boff[blockIdx.x] + excl;
    if (i < N_NODES) { row_start[i] = r; pos[i] = r; }
    if (i == 0) row_start[N_NODES] = N_EDGES;
}

// pass A fill: scatter edges into src-sorted order
__global__ __launch_bounds__(256) void fill_by_src(
    const int* __restrict__ esrc, const int* __restrict__ edst,
    const float* __restrict__ ew, int* __restrict__ pos,
    int* __restrict__ e_src, int* __restrict__ e_dst, float* __restrict__ e_w)
{
    int i = blockIdx.x * 256 + threadIdx.x;
    if (i < N_EDGES) {
        int s = esrc[i];
        int p = atomicAdd(&pos[s], 1);
        e_src[p] = s;
        e_dst[p] = edst[i];
        e_w[p]   = 0.9f * ew[i];   // fold (1-ALPHA)
    }
}

// pass B fill: scatter src-sorted edges into dst-CSR (rows end up ~src-sorted)
__global__ __launch_bounds__(256) void fill_by_dst(
    const int* __restrict__ e_src, const int* __restrict__ e_dst,
    const float* __restrict__ e_w, int* __restrict__ pos,
    int* __restrict__ csr_src, float* __restrict__ csr_w)
{
    int p = blockIdx.x * 256 + threadIdx.x;
    if (p < N_EDGES) {
        int d = e_dst[p];
        int q = atomicAdd(&pos[d], 1);
        csr_src[q] = e_src[p];
        csr_w[q]   = e_w[p];
    }
}

// ---------------------------------------------------------------------------
// Pull-based SpMM, bf16 z: zout[d] = ahb[d] + sum_j w[j] * zin[csr_src[j]]
// One wave per dst node, lane = feature. fp32 accumulate.
// ---------------------------------------------------------------------------
template <bool FINAL>
__global__ __launch_bounds__(256) void spmm_kernel(
    const int* __restrict__ row_start, const int* __restrict__ csr_src,
    const float* __restrict__ csr_w, const ushort_t* __restrict__ zin,
    const ushort_t* __restrict__ ahb, void* __restrict__ zout)
{
    const int node = blockIdx.x * 4 + (threadIdx.x >> 6);  // 25000*4 == 100000
    const int f = threadIdx.x & 63;
    const int s0 = __builtin_amdgcn_readfirstlane(row_start[node]);
    const int s1 = __builtin_amdgcn_readfirstlane(row_start[node + 1]);
    float acc = bf2f(ahb[node * 64 + f]);
    int j = s0;
    for (; j + 8 <= s1; j += 8) {
        int a0 = csr_src[j+0], a1 = csr_src[j+1], a2 = csr_src[j+2], a3 = csr_src[j+3];
        int a4 = csr_src[j+4], a5 = csr_src[j+5], a6 = csr_src[j+6], a7 = csr_src[j+7];
        float w0 = csr_w[j+0], w1 = csr_w[j+1], w2 = csr_w[j+2], w3 = csr_w[j+3];
        float w4 = csr_w[j+4], w5 = csr_w[j+5], w6 = csr_w[j+6], w7 = csr_w[j+7];
        float v0 = bf2f(zin[a0*64+f]), v1 = bf2f(zin[a1*64+f]);
        float v2 = bf2f(zin[a2*64+f]), v3 = bf2f(zin[a3*64+f]);
        float v4 = bf2f(zin[a4*64+f]), v5 = bf2f(zin[a5*64+f]);
        float v6 = bf2f(zin[a6*64+f]), v7 = bf2f(zin[a7*64+f]);
        acc = fmaf(w0, v0, acc); acc = fmaf(w1, v1, acc);
        acc = fmaf(w2, v2, acc); acc = fmaf(w3, v3, acc);
        acc = fmaf(w4, v4, acc); acc = fmaf(w5, v5, acc);
        acc = fmaf(w6, v6, acc); acc = fmaf(w7, v7, acc);
    }
    for (; j < s1; ++j)
        acc = fmaf(csr_w[j], bf2f(zin[csr_src[j]*64 + f]), acc);
    if (FINAL) ((float*)zout)[node * 64 + f] = acc;
    else       ((ushort_t*)zout)[node * 64 + f] = f2b(acc);
}

// ---------------------------------------------------------------------------
extern "C" void kernel_launch(void* const* d_in, const int* in_sizes, int n_in,
                              void* d_out, int out_size, void* d_ws, size_t ws_size,
                              hipStream_t stream)
{
    const float* x    = (const float*)d_in[0];
    const int*   esrc = (const int*)d_in[1];
    const int*   edst = (const int*)d_in[2];
    const float* ew   = (const float*)d_in[3];
    const float* W1   = (const float*)d_in[4];
    const float* b1   = (const float*)d_in[5];
    const float* W2   = (const float*)d_in[6];
    const float* b2   = (const float*)d_in[7];
    float* out = (float*)d_out;

    // workspace layout (~103.5 MB)
    char* p = (char*)d_ws;
    ushort_t* ahb = (ushort_t*)p;  p += (size_t)N_NODES * 64 * 2;   // 12.8M
    ushort_t* hb  = (ushort_t*)p;  p += (size_t)N_NODES * 64 * 2;   // 12.8M (doubles as ping-pong buf)
    ushort_t* zB  = (ushort_t*)p;  p += (size_t)N_NODES * 64 * 2;   // 12.8M
    int*   e_src   = (int*)p;      p += (size_t)N_EDGES * 4;        // 12.8M
    int*   e_dst   = (int*)p;      p += (size_t)N_EDGES * 4;        // 12.8M
    float* e_w     = (float*)p;    p += (size_t)N_EDGES * 4;        // 12.8M
    int*   csr_src = (int*)p;      p += (size_t)N_EDGES * 4;        // 12.8M
    float* csr_w   = (float*)p;    p += (size_t)N_EDGES * 4;        // 12.8M
    int* cnt       = (int*)p;      p += (size_t)N_NODES * 4;
    int* pos       = (int*)p;      p += (size_t)N_NODES * 4;
    int* row_start = (int*)p;      p += (size_t)(N_NODES + 1) * 4;
    int* bsum      = (int*)p;      p += (size_t)SCAN_B * 4;
    int* boff      = (int*)p;      p += (size_t)SCAN_B * 4;

    const int EB = (N_EDGES + 255) / 256;

    hipLaunchKernelGGL(mlp_kernel, dim3(N_NODES / 16), dim3(256), 0, stream,
                       x, W1, b1, W2, b2, hb, ahb);

    // pass A: counting sort by src
    hipLaunchKernelGGL(zero_cnt, dim3(SCAN_B), dim3(256), 0, stream, cnt);
    hipLaunchKernelGGL(count_keys, dim3(EB), dim3(256), 0, stream, esrc, cnt);
    hipLaunchKernelGGL(scan_block_sums, dim3(SCAN_B), dim3(256), 0, stream, cnt, bsum);
    hipLaunchKernelGGL(scan_partials, dim3(1), dim3(512), 0, stream, bsum, boff);
    hipLaunchKernelGGL(scan_final, dim3(SCAN_B), dim3(256), 0, stream,
                       cnt, boff, row_start, pos);
    hipLaunchKernelGGL(fill_by_src, dim3(EB), dim3(256), 0, stream,
                       esrc, edst, ew, pos, e_src, e_dst, e_w);

    // pass B: counting sort by dst (rows become ~src-sorted)
    hipLaunchKernelGGL(zero_cnt, dim3(SCAN_B), dim3(256), 0, stream, cnt);
    hipLaunchKernelGGL(count_keys, dim3(EB), dim3(256), 0, stream, e_dst, cnt);
    hipLaunchKernelGGL(scan_block_sums, dim3(SCAN_B), dim3(256), 0, stream, cnt, bsum);
    hipLaunchKernelGGL(scan_partials, dim3(1), dim3(512), 0, stream, bsum, boff);
    hipLaunchKernelGGL(scan_final, dim3(SCAN_B), dim3(256), 0, stream,
                       cnt, boff, row_start, pos);
    hipLaunchKernelGGL(fill_by_dst, dim3(EB), dim3(256), 0, stream,
                       e_src, e_dst, e_w, pos, csr_src, csr_w);

    // propagation: strict alternation. it even: ->zB, it odd: ->hb.
    // it=0: hb->zB; it=1: zB->hb; ... it=8: hb->zB; final (it=9): zB->out(fp32).
    // Input buffer != output buffer at every step by construction.
    const ushort_t* zi = hb;
    for (int it = 0; it < K_ITERS - 1; ++it) {
        ushort_t* zo = (it % 2 == 0) ? zB : hb;
        hipLaunchKernelGGL((spmm_kernel<false>), dim3(N_NODES / 4), dim3(256), 0, stream,
                           row_start, csr_src, csr_w, zi, ahb, (void*)zo);
        zi = zo;
    }
    hipLaunchKernelGGL((spmm_kernel<true>), dim3(N_NODES / 4), dim3(256), 0, stream,
                       row_start, csr_src, csr_w, zi, ahb, (void*)out);
}

// Round 4
// 1583.412 us; speedup vs baseline: 1.3526x; 1.1851x over previous
//
#include <hip/hip_runtime.h>

#define N_NODES 100000
#define N_EDGES 3200000
#define IN_F 500
#define HID 64
#define OUT_F 64
#define ALPHA 0.1f
#define K_ITERS 10
#define SCAN_B ((N_NODES + 255) / 256)   // 391

typedef unsigned short ushort_t;
typedef unsigned int uint_t;

__device__ __forceinline__ float bf2f(ushort_t v) {
    union { uint_t u; float f; } c; c.u = ((uint_t)v) << 16; return c.f;
}
__device__ __forceinline__ ushort_t f2b(float f) {
    union { float f; uint_t u; } c; c.f = f;
    uint_t u = c.u + 0x7fffu + ((c.u >> 16) & 1u);   // round-to-nearest-even
    return (ushort_t)(u >> 16);
}

// ---------------------------------------------------------------------------
// Fused MLP: v = relu(x@W1+b1)@W2+b2 ; writes hb = bf16(v), ahb = bf16(ALPHA*v)
// Block = 256 = 4 waves; block does 32 rows x 64 cols; wave rg does rows
// rg*8..rg*8+7. Inner loop: 32 FMA per 12 mem ops (8 ds_read_b128 + 4 global).
// ---------------------------------------------------------------------------
__global__ __launch_bounds__(256) void mlp_kernel(
    const float* __restrict__ x, const float* __restrict__ W1,
    const float* __restrict__ b1, const float* __restrict__ W2,
    const float* __restrict__ b2, ushort_t* __restrict__ hb,
    ushort_t* __restrict__ ahb)
{
    __shared__ float xs[32][100];   // 12.8 KB
    __shared__ float hid[32][64];   // 8 KB
    __shared__ float w2s[64][64];   // 16 KB

    const int tid = threadIdx.x;
    const int c   = tid & 63;
    const int rg  = tid >> 6;
    const int block_row = blockIdx.x * 32;   // 3125*32 == 100000

    float acc[8] = {0.f, 0.f, 0.f, 0.f, 0.f, 0.f, 0.f, 0.f};

    for (int kb = 0; kb < IN_F; kb += 100) {
        // stage 32x100 chunk of x as float4 (800 float4s)
        for (int i = tid; i < 800; i += 256) {
            int r = i / 25, c4 = i - r * 25;
            *(float4*)&xs[r][c4 * 4] =
                *(const float4*)&x[(long)(block_row + r) * IN_F + kb + c4 * 4];
        }
        __syncthreads();
        for (int k = 0; k < 100; k += 4) {
            float w0 = W1[(kb+k+0)*HID + c];
            float w1 = W1[(kb+k+1)*HID + c];
            float w2 = W1[(kb+k+2)*HID + c];
            float w3 = W1[(kb+k+3)*HID + c];
            #pragma unroll
            for (int r = 0; r < 8; ++r) {
                float4 xv = *(const float4*)&xs[rg*8+r][k];
                acc[r] = fmaf(xv.x, w0, acc[r]);
                acc[r] = fmaf(xv.y, w1, acc[r]);
                acc[r] = fmaf(xv.z, w2, acc[r]);
                acc[r] = fmaf(xv.w, w3, acc[r]);
            }
        }
        __syncthreads();
    }

    float b = b1[c];
    #pragma unroll
    for (int r = 0; r < 8; ++r)
        hid[rg*8+r][c] = fmaxf(acc[r] + b, 0.f);
    for (int i = tid; i < 64 * 64; i += 256) w2s[i >> 6][i & 63] = W2[i];
    __syncthreads();

    float o[8] = {0.f, 0.f, 0.f, 0.f, 0.f, 0.f, 0.f, 0.f};
    for (int k = 0; k < HID; k += 4) {
        float w0 = w2s[k+0][c], w1 = w2s[k+1][c];
        float w2 = w2s[k+2][c], w3 = w2s[k+3][c];
        #pragma unroll
        for (int r = 0; r < 8; ++r) {
            float4 hv = *(const float4*)&hid[rg*8+r][k];
            o[r] = fmaf(hv.x, w0, o[r]);
            o[r] = fmaf(hv.y, w1, o[r]);
            o[r] = fmaf(hv.z, w2, o[r]);
            o[r] = fmaf(hv.w, w3, o[r]);
        }
    }
    float bb = b2[c];
    int r0 = block_row + rg * 8;
    #pragma unroll
    for (int r = 0; r < 8; ++r) {
        float v = o[r] + bb;
        hb[(r0+r)*64 + c]  = f2b(v);
        ahb[(r0+r)*64 + c] = f2b(ALPHA * v);
    }
}

// ---------------------------------------------------------------------------
// CSR build: count -> 2-level exclusive scan -> packed atomic fill -> row sort
// ---------------------------------------------------------------------------
__global__ __launch_bounds__(256) void zero_cnt(int* __restrict__ cnt)
{
    int i = blockIdx.x * 256 + threadIdx.x;
    if (i < N_NODES) cnt[i] = 0;
}

__global__ __launch_bounds__(256) void count_keys(
    const int* __restrict__ key, int* __restrict__ cnt)
{
    int i = blockIdx.x * 256 + threadIdx.x;
    if (i < N_EDGES) atomicAdd(&cnt[key[i]], 1);
}

__global__ __launch_bounds__(256) void scan_block_sums(
    const int* __restrict__ cnt, int* __restrict__ bsum)
{
    int i = blockIdx.x * 256 + threadIdx.x;
    int v = (i < N_NODES) ? cnt[i] : 0;
    for (int off = 32; off; off >>= 1) v += __shfl_down(v, off);
    __shared__ int ws_[4];
    if ((threadIdx.x & 63) == 0) ws_[threadIdx.x >> 6] = v;
    __syncthreads();
    if (threadIdx.x == 0) bsum[blockIdx.x] = ws_[0] + ws_[1] + ws_[2] + ws_[3];
}

__global__ __launch_bounds__(512) void scan_partials(
    const int* __restrict__ bsum, int* __restrict__ boff)
{
    int t = threadIdx.x;
    int v = (t < SCAN_B) ? bsum[t] : 0;
    int lane = t & 63, w = t >> 6;
    int x = v;
    for (int off = 1; off < 64; off <<= 1) {
        int y = __shfl_up(x, off);
        if (lane >= off) x += y;
    }
    __shared__ int wsum[8];
    if (lane == 63) wsum[w] = x;
    __syncthreads();
    if (w == 0) {
        int s = (lane < 8) ? wsum[lane] : 0;
        for (int off = 1; off < 8; off <<= 1) {
            int y = __shfl_up(s, off);
            if (lane >= off) s += y;
        }
        if (lane < 8) wsum[lane] = s;
    }
    __syncthreads();
    int wpre = (w == 0) ? 0 : wsum[w - 1];
    if (t < SCAN_B) boff[t] = wpre + x - v;
}

__global__ __launch_bounds__(256) void scan_final(
    const int* __restrict__ cnt, const int* __restrict__ boff,
    int* __restrict__ row_start, int* __restrict__ pos)
{
    int i = blockIdx.x * 256 + threadIdx.x;
    int v = (i < N_NODES) ? cnt[i] : 0;
    int lane = threadIdx.x & 63, w = threadIdx.x >> 6;
    int x = v;
    for (int off = 1; off < 64; off <<= 1) {
        int y = __shfl_up(x, off);
        if (lane >= off) x += y;
    }
    __shared__ int wsum[4];
    if (lane == 63) wsum[w] = x;
    __syncthreads();
    int wpre = 0;
    for (int ww = 0; ww < w; ++ww) wpre += wsum[ww];
    int excl = wpre + x - v;
    int r = boff[blockIdx.x] + excl;
    if (i < N_NODES) { row_start[i] = r; pos[i] = r; }
    if (i == 0) row_start[N_NODES] = N_EDGES;
}

// Direct dst-CSR fill: one packed 8B store per edge (src, 0.9*w)
__global__ __launch_bounds__(256) void fill_dst(
    const int* __restrict__ esrc, const int* __restrict__ edst,
    const float* __restrict__ ew, int* __restrict__ pos,
    int2* __restrict__ csr)
{
    int i = blockIdx.x * 256 + threadIdx.x;
    if (i < N_EDGES) {
        int d = edst[i];
        int q = atomicAdd(&pos[d], 1);
        float w = 0.9f * ew[i];             // fold (1-ALPHA)
        csr[q] = make_int2(esrc[i], __float_as_int(w));
    }
}

// In-row bitonic sort by src (locality only — correctness never depends on
// order). One wave per row; sorts first min(len,64) entries; longer tails
// (probability ~0 at Poisson(32)) are left unsorted, which is still correct.
__global__ __launch_bounds__(256) void sort_rows(
    const int* __restrict__ row_start, int2* __restrict__ csr)
{
    const int node = blockIdx.x * 4 + (threadIdx.x >> 6);
    const int lane = threadIdx.x & 63;
    const int s0 = row_start[node];
    const int s1 = row_start[node + 1];
    int n = s1 - s0; if (n > 64) n = 64;
    int key = 0x7fffffff;
    int val = 0;
    if (lane < n) { int2 e = csr[s0 + lane]; key = e.x; val = e.y; }
    #pragma unroll
    for (int k = 2; k <= 64; k <<= 1) {
        #pragma unroll
        for (int j = k >> 1; j > 0; j >>= 1) {
            int pk = __shfl_xor(key, j, 64);
            int pv = __shfl_xor(val, j, 64);
            bool lower   = (lane & j) == 0;
            bool asc     = (lane & k) == 0;
            bool takeMin = (lower == asc);
            bool pick    = takeMin ? (pk < key) : (pk > key);
            if (pick) { key = pk; val = pv; }
        }
    }
    if (lane < n) csr[s0 + lane] = make_int2(key, val);
}

// ---------------------------------------------------------------------------
// Pull-based SpMM, bf16 z: zout[d] = ahb[d] + sum_j w[j] * zin[src[j]]
// One wave per dst node, lane = feature. fp32 accumulate. CSR packed int2,
// wave-uniform indices (scalar-load friendly).
// ---------------------------------------------------------------------------
template <bool FINAL>
__global__ __launch_bounds__(256) void spmm_kernel(
    const int* __restrict__ row_start, const int2* __restrict__ csr,
    const ushort_t* __restrict__ zin, const ushort_t* __restrict__ ahb,
    void* __restrict__ zout)
{
    const int node = blockIdx.x * 4 + (threadIdx.x >> 6);  // 25000*4 == 100000
    const int f = threadIdx.x & 63;
    const int s0 = __builtin_amdgcn_readfirstlane(row_start[node]);
    const int s1 = __builtin_amdgcn_readfirstlane(row_start[node + 1]);
    float acc = bf2f(ahb[node * 64 + f]);
    int j = s0;
    for (; j + 8 <= s1; j += 8) {
        int2 e0 = csr[j+0], e1 = csr[j+1], e2 = csr[j+2], e3 = csr[j+3];
        int2 e4 = csr[j+4], e5 = csr[j+5], e6 = csr[j+6], e7 = csr[j+7];
        float v0 = bf2f(zin[e0.x*64+f]), v1 = bf2f(zin[e1.x*64+f]);
        float v2 = bf2f(zin[e2.x*64+f]), v3 = bf2f(zin[e3.x*64+f]);
        float v4 = bf2f(zin[e4.x*64+f]), v5 = bf2f(zin[e5.x*64+f]);
        float v6 = bf2f(zin[e6.x*64+f]), v7 = bf2f(zin[e7.x*64+f]);
        acc = fmaf(__int_as_float(e0.y), v0, acc);
        acc = fmaf(__int_as_float(e1.y), v1, acc);
        acc = fmaf(__int_as_float(e2.y), v2, acc);
        acc = fmaf(__int_as_float(e3.y), v3, acc);
        acc = fmaf(__int_as_float(e4.y), v4, acc);
        acc = fmaf(__int_as_float(e5.y), v5, acc);
        acc = fmaf(__int_as_float(e6.y), v6, acc);
        acc = fmaf(__int_as_float(e7.y), v7, acc);
    }
    for (; j < s1; ++j) {
        int2 e = csr[j];
        acc = fmaf(__int_as_float(e.y), bf2f(zin[e.x*64 + f]), acc);
    }
    if (FINAL) ((float*)zout)[node * 64 + f] = acc;
    else       ((ushort_t*)zout)[node * 64 + f] = f2b(acc);
}

// ---------------------------------------------------------------------------
extern "C" void kernel_launch(void* const* d_in, const int* in_sizes, int n_in,
                              void* d_out, int out_size, void* d_ws, size_t ws_size,
                              hipStream_t stream)
{
    const float* x    = (const float*)d_in[0];
    const int*   esrc = (const int*)d_in[1];
    const int*   edst = (const int*)d_in[2];
    const float* ew   = (const float*)d_in[3];
    const float* W1   = (const float*)d_in[4];
    const float* b1   = (const float*)d_in[5];
    const float* W2   = (const float*)d_in[6];
    const float* b2   = (const float*)d_in[7];
    float* out = (float*)d_out;

    // workspace layout (~65 MB)
    char* p = (char*)d_ws;
    ushort_t* ahb = (ushort_t*)p;  p += (size_t)N_NODES * 64 * 2;   // 12.8M
    ushort_t* hb  = (ushort_t*)p;  p += (size_t)N_NODES * 64 * 2;   // 12.8M (ping-pong buf)
    ushort_t* zB  = (ushort_t*)p;  p += (size_t)N_NODES * 64 * 2;   // 12.8M
    int2*  csr     = (int2*)p;     p += (size_t)N_EDGES * 8;        // 25.6M
    int* cnt       = (int*)p;      p += (size_t)N_NODES * 4;
    int* pos       = (int*)p;      p += (size_t)N_NODES * 4;
    int* row_start = (int*)p;      p += (size_t)(N_NODES + 1) * 4;
    int* bsum      = (int*)p;      p += (size_t)SCAN_B * 4;
    int* boff      = (int*)p;      p += (size_t)SCAN_B * 4;

    const int EB = (N_EDGES + 255) / 256;

    hipLaunchKernelGGL(mlp_kernel, dim3(N_NODES / 32), dim3(256), 0, stream,
                       x, W1, b1, W2, b2, hb, ahb);

    // counting sort by dst, packed payload, then in-row sort by src
    hipLaunchKernelGGL(zero_cnt, dim3(SCAN_B), dim3(256), 0, stream, cnt);
    hipLaunchKernelGGL(count_keys, dim3(EB), dim3(256), 0, stream, edst, cnt);
    hipLaunchKernelGGL(scan_block_sums, dim3(SCAN_B), dim3(256), 0, stream, cnt, bsum);
    hipLaunchKernelGGL(scan_partials, dim3(1), dim3(512), 0, stream, bsum, boff);
    hipLaunchKernelGGL(scan_final, dim3(SCAN_B), dim3(256), 0, stream,
                       cnt, boff, row_start, pos);
    hipLaunchKernelGGL(fill_dst, dim3(EB), dim3(256), 0, stream,
                       esrc, edst, ew, pos, csr);
    hipLaunchKernelGGL(sort_rows, dim3(N_NODES / 4), dim3(256), 0, stream,
                       row_start, csr);

    // propagation: strict alternation. it even: ->zB, it odd: ->hb.
    // it=0: hb->zB; it=1: zB->hb; ... it=8: hb->zB; final (it=9): zB->out(fp32).
    const ushort_t* zi = hb;
    for (int it = 0; it < K_ITERS - 1; ++it) {
        ushort_t* zo = (it % 2 == 0) ? zB : hb;
        hipLaunchKernelGGL((spmm_kernel<false>), dim3(N_NODES / 4), dim3(256), 0, stream,
                           row_start, csr, zi, ahb, (void*)zo);
        zi = zo;
    }
    hipLaunchKernelGGL((spmm_kernel<true>), dim3(N_NODES / 4), dim3(256), 0, stream,
                       row_start, csr, zi, ahb, (void*)out);
}

// Round 6
// 1446.217 us; speedup vs baseline: 1.4810x; 1.0949x over previous
//
#include <hip/hip_runtime.h>

#define N_NODES 100000
#define N_EDGES 3200000
#define IN_F 500
#define HID 64
#define OUT_F 64
#define ALPHA 0.1f
#define K_ITERS 10
#define SCAN_B ((N_NODES + 255) / 256)   // 391

typedef unsigned short ushort_t;
typedef unsigned int uint_t;

__device__ __forceinline__ float bf2f(ushort_t v) {
    union { uint_t u; float f; } c; c.u = ((uint_t)v) << 16; return c.f;
}
__device__ __forceinline__ ushort_t f2b(float f) {
    union { float f; uint_t u; } c; c.f = f;
    uint_t u = c.u + 0x7fffu + ((c.u >> 16) & 1u);   // round-to-nearest-even
    return (ushort_t)(u >> 16);
}
__device__ __forceinline__ float bflo(uint_t u) {
    union { uint_t u; float f; } c; c.u = u << 16; return c.f;
}
__device__ __forceinline__ float bfhi(uint_t u) {
    union { uint_t u; float f; } c; c.u = u & 0xffff0000u; return c.f;
}
__device__ __forceinline__ uint_t packbf(float a, float b) {
    return (uint_t)f2b(a) | ((uint_t)f2b(b) << 16);
}

// ---------------------------------------------------------------------------
// Fused MLP: v = relu(x@W1+b1)@W2+b2 ; writes hb = bf16(v), ahb = bf16(ALPHA*v)
// Block = 256 = 4 waves; 32 rows x 64 cols; wave rg does rows rg*8..+7.
// W1/W2 read from global (L1-hot); only x and hid staged in LDS (20.8 KB ->
// 7 blocks/CU occupancy).
// ---------------------------------------------------------------------------
__global__ __launch_bounds__(256) void mlp_kernel(
    const float* __restrict__ x, const float* __restrict__ W1,
    const float* __restrict__ b1, const float* __restrict__ W2,
    const float* __restrict__ b2, ushort_t* __restrict__ hb,
    ushort_t* __restrict__ ahb)
{
    __shared__ float xs[32][100];   // 12.8 KB
    __shared__ float hid[32][64];   // 8 KB

    const int tid = threadIdx.x;
    const int c   = tid & 63;
    const int rg  = tid >> 6;
    const int block_row = blockIdx.x * 32;   // 3125*32 == 100000

    float acc[8] = {0.f, 0.f, 0.f, 0.f, 0.f, 0.f, 0.f, 0.f};

    for (int kb = 0; kb < IN_F; kb += 100) {
        for (int i = tid; i < 800; i += 256) {
            int r = i / 25, c4 = i - r * 25;
            *(float4*)&xs[r][c4 * 4] =
                *(const float4*)&x[(long)(block_row + r) * IN_F + kb + c4 * 4];
        }
        __syncthreads();
        for (int k = 0; k < 100; k += 4) {
            float w0 = W1[(kb+k+0)*HID + c];
            float w1 = W1[(kb+k+1)*HID + c];
            float w2 = W1[(kb+k+2)*HID + c];
            float w3 = W1[(kb+k+3)*HID + c];
            #pragma unroll
            for (int r = 0; r < 8; ++r) {
                float4 xv = *(const float4*)&xs[rg*8+r][k];
                acc[r] = fmaf(xv.x, w0, acc[r]);
                acc[r] = fmaf(xv.y, w1, acc[r]);
                acc[r] = fmaf(xv.z, w2, acc[r]);
                acc[r] = fmaf(xv.w, w3, acc[r]);
            }
        }
        __syncthreads();
    }

    float b = b1[c];
    #pragma unroll
    for (int r = 0; r < 8; ++r)
        hid[rg*8+r][c] = fmaxf(acc[r] + b, 0.f);
    __syncthreads();

    float o[8] = {0.f, 0.f, 0.f, 0.f, 0.f, 0.f, 0.f, 0.f};
    for (int k = 0; k < HID; k += 4) {
        float w0 = W2[(k+0)*OUT_F + c], w1 = W2[(k+1)*OUT_F + c];
        float w2 = W2[(k+2)*OUT_F + c], w3 = W2[(k+3)*OUT_F + c];
        #pragma unroll
        for (int r = 0; r < 8; ++r) {
            float4 hv = *(const float4*)&hid[rg*8+r][k];
            o[r] = fmaf(hv.x, w0, o[r]);
            o[r] = fmaf(hv.y, w1, o[r]);
            o[r] = fmaf(hv.z, w2, o[r]);
            o[r] = fmaf(hv.w, w3, o[r]);
        }
    }
    float bb = b2[c];
    int r0 = block_row + rg * 8;
    #pragma unroll
    for (int r = 0; r < 8; ++r) {
        float v = o[r] + bb;
        hb[(r0+r)*64 + c]  = f2b(v);
        ahb[(r0+r)*64 + c] = f2b(ALPHA * v);
    }
}

// ---------------------------------------------------------------------------
// CSR build: count -> 2-level exclusive scan -> packed atomic fill -> row sort
// ---------------------------------------------------------------------------
__global__ __launch_bounds__(256) void zero_cnt(int* __restrict__ cnt)
{
    int i = blockIdx.x * 256 + threadIdx.x;
    if (i < N_NODES) cnt[i] = 0;
}

__global__ __launch_bounds__(256) void count_keys(
    const int* __restrict__ key, int* __restrict__ cnt)
{
    int i = blockIdx.x * 256 + threadIdx.x;
    if (i < N_EDGES) atomicAdd(&cnt[key[i]], 1);
}

__global__ __launch_bounds__(256) void scan_block_sums(
    const int* __restrict__ cnt, int* __restrict__ bsum)
{
    int i = blockIdx.x * 256 + threadIdx.x;
    int v = (i < N_NODES) ? cnt[i] : 0;
    for (int off = 32; off; off >>= 1) v += __shfl_down(v, off);
    __shared__ int ws_[4];
    if ((threadIdx.x & 63) == 0) ws_[threadIdx.x >> 6] = v;
    __syncthreads();
    if (threadIdx.x == 0) bsum[blockIdx.x] = ws_[0] + ws_[1] + ws_[2] + ws_[3];
}

__global__ __launch_bounds__(512) void scan_partials(
    const int* __restrict__ bsum, int* __restrict__ boff)
{
    int t = threadIdx.x;
    int v = (t < SCAN_B) ? bsum[t] : 0;
    int lane = t & 63, w = t >> 6;
    int x = v;
    for (int off = 1; off < 64; off <<= 1) {
        int y = __shfl_up(x, off);
        if (lane >= off) x += y;
    }
    __shared__ int wsum[8];
    if (lane == 63) wsum[w] = x;
    __syncthreads();
    if (w == 0) {
        int s = (lane < 8) ? wsum[lane] : 0;
        for (int off = 1; off < 8; off <<= 1) {
            int y = __shfl_up(s, off);
            if (lane >= off) s += y;
        }
        if (lane < 8) wsum[lane] = s;
    }
    __syncthreads();
    int wpre = (w == 0) ? 0 : wsum[w - 1];
    if (t < SCAN_B) boff[t] = wpre + x - v;
}

__global__ __launch_bounds__(256) void scan_final(
    const int* __restrict__ cnt, const int* __restrict__ boff,
    int* __restrict__ row_start, int* __restrict__ pos)
{
    int i = blockIdx.x * 256 + threadIdx.x;
    int v = (i < N_NODES) ? cnt[i] : 0;
    int lane = threadIdx.x & 63, w = threadIdx.x >> 6;
    int x = v;
    for (int off = 1; off < 64; off <<= 1) {
        int y = __shfl_up(x, off);
        if (lane >= off) x += y;
    }
    __shared__ int wsum[4];
    if (lane == 63) wsum[w] = x;
    __syncthreads();
    int wpre = 0;
    for (int ww = 0; ww < w; ++ww) wpre += wsum[ww];
    int excl = wpre + x - v;
    int r = boff[blockIdx.x] + excl;
    if (i < N_NODES) { row_start[i] = r; pos[i] = r; }
    if (i == 0) row_start[N_NODES] = N_EDGES;
}

// Direct dst-CSR fill: one packed 8B store per edge (src, 0.9*w)
__global__ __launch_bounds__(256) void fill_dst(
    const int* __restrict__ esrc, const int* __restrict__ edst,
    const float* __restrict__ ew, int* __restrict__ pos,
    int2* __restrict__ csr)
{
    int i = blockIdx.x * 256 + threadIdx.x;
    if (i < N_EDGES) {
        int d = edst[i];
        int q = atomicAdd(&pos[d], 1);
        float w = 0.9f * ew[i];             // fold (1-ALPHA)
        csr[q] = make_int2(esrc[i], __float_as_int(w));
    }
}

// In-row bitonic sort by src (locality only — correctness never depends on
// order). One wave per row; sorts first min(len,64) entries.
__global__ __launch_bounds__(256) void sort_rows(
    const int* __restrict__ row_start, int2* __restrict__ csr)
{
    const int node = blockIdx.x * 4 + (threadIdx.x >> 6);
    const int lane = threadIdx.x & 63;
    const int s0 = row_start[node];
    const int s1 = row_start[node + 1];
    int n = s1 - s0; if (n > 64) n = 64;
    int key = 0x7fffffff;
    int val = 0;
    if (lane < n) { int2 e = csr[s0 + lane]; key = e.x; val = e.y; }
    #pragma unroll
    for (int k = 2; k <= 64; k <<= 1) {
        #pragma unroll
        for (int j = k >> 1; j > 0; j >>= 1) {
            int pk = __shfl_xor(key, j, 64);
            int pv = __shfl_xor(val, j, 64);
            bool lower   = (lane & j) == 0;
            bool asc     = (lane & k) == 0;
            bool takeMin = (lower == asc);
            bool pick    = takeMin ? (pk < key) : (pk > key);
            if (pick) { key = pk; val = pv; }
        }
    }
    if (lane < n) csr[s0 + lane] = make_int2(key, val);
}

// ---------------------------------------------------------------------------
// Pull-based SpMM, bf16 z. One wave per dst node. 8 lanes x 16 B cover one
// z-row (64 bf16): one global_load_dwordx4 gathers 8 edges -> 8 distinct
// 128 B lines per VMEM instr. Unroll 4 => 32 edge-lines in flight per wave.
// Group g = lane>>3 owns edge slot; q = lane&7 owns features 8q..8q+7.
// Row-end reduction: 3 shfl_xor rounds over groups.
// NOTE: macro params named WV/ZV — .x/.y/.z/.w member tokens must NOT
// collide with parameter names (round-5 compile failure).
// ---------------------------------------------------------------------------
template <bool FINAL>
__global__ __launch_bounds__(256) void spmm_kernel(
    const int* __restrict__ row_start, const int2* __restrict__ csr,
    const ushort_t* __restrict__ zin, const ushort_t* __restrict__ ahb,
    void* __restrict__ zout)
{
    const int node = blockIdx.x * 4 + (threadIdx.x >> 6);  // 25000*4 == 100000
    const int lane = threadIdx.x & 63;
    const int g = lane >> 3;    // edge slot 0..7
    const int q = lane & 7;     // feature octet
    const int s0 = __builtin_amdgcn_readfirstlane(row_start[node]);
    const int s1 = __builtin_amdgcn_readfirstlane(row_start[node + 1]);

    float a0=0.f,a1=0.f,a2=0.f,a3=0.f,a4=0.f,a5=0.f,a6=0.f,a7=0.f;
    if (g == 0) {
        uint4 t = *(const uint4*)&ahb[node * 64 + 8 * q];
        a0 = bflo(t.x); a1 = bfhi(t.x); a2 = bflo(t.y); a3 = bfhi(t.y);
        a4 = bflo(t.z); a5 = bfhi(t.z); a6 = bflo(t.w); a7 = bfhi(t.w);
    }

#define FMA8(WV, ZV) do { \
        a0 = fmaf((WV), bflo((ZV).x), a0); a1 = fmaf((WV), bfhi((ZV).x), a1); \
        a2 = fmaf((WV), bflo((ZV).y), a2); a3 = fmaf((WV), bfhi((ZV).y), a3); \
        a4 = fmaf((WV), bflo((ZV).z), a4); a5 = fmaf((WV), bfhi((ZV).z), a5); \
        a6 = fmaf((WV), bflo((ZV).w), a6); a7 = fmaf((WV), bfhi((ZV).w), a7); \
    } while (0)

    int j = s0;
    for (; j + 32 <= s1; j += 32) {
        int2 e0 = csr[j + g];
        int2 e1 = csr[j + 8 + g];
        int2 e2 = csr[j + 16 + g];
        int2 e3 = csr[j + 24 + g];
        uint4 z0 = *(const uint4*)&zin[e0.x * 64 + 8 * q];
        uint4 z1 = *(const uint4*)&zin[e1.x * 64 + 8 * q];
        uint4 z2 = *(const uint4*)&zin[e2.x * 64 + 8 * q];
        uint4 z3 = *(const uint4*)&zin[e3.x * 64 + 8 * q];
        float w0 = __int_as_float(e0.y);
        float w1 = __int_as_float(e1.y);
        float w2 = __int_as_float(e2.y);
        float w3 = __int_as_float(e3.y);
        FMA8(w0, z0);
        FMA8(w1, z1);
        FMA8(w2, z2);
        FMA8(w3, z3);
    }
    for (; j < s1; j += 8) {
        int2 e = make_int2(0, 0);
        int jj = j + g;
        if (jj < s1) e = csr[jj];
        uint4 zt = *(const uint4*)&zin[e.x * 64 + 8 * q];
        float wt = __int_as_float(e.y);
        FMA8(wt, zt);
    }
#undef FMA8

    // reduce the 8 edge-slot groups (lane bits 3,4,5)
    #pragma unroll
    for (int m = 8; m <= 32; m <<= 1) {
        a0 += __shfl_xor(a0, m, 64); a1 += __shfl_xor(a1, m, 64);
        a2 += __shfl_xor(a2, m, 64); a3 += __shfl_xor(a3, m, 64);
        a4 += __shfl_xor(a4, m, 64); a5 += __shfl_xor(a5, m, 64);
        a6 += __shfl_xor(a6, m, 64); a7 += __shfl_xor(a7, m, 64);
    }

    if (g == 0) {
        if (FINAL) {
            float* op = (float*)zout + node * 64 + 8 * q;
            *(float4*)op       = make_float4(a0, a1, a2, a3);
            *(float4*)(op + 4) = make_float4(a4, a5, a6, a7);
        } else {
            uint4 pk;
            pk.x = packbf(a0, a1); pk.y = packbf(a2, a3);
            pk.z = packbf(a4, a5); pk.w = packbf(a6, a7);
            *(uint4*)&((ushort_t*)zout)[node * 64 + 8 * q] = pk;
        }
    }
}

// ---------------------------------------------------------------------------
extern "C" void kernel_launch(void* const* d_in, const int* in_sizes, int n_in,
                              void* d_out, int out_size, void* d_ws, size_t ws_size,
                              hipStream_t stream)
{
    const float* x    = (const float*)d_in[0];
    const int*   esrc = (const int*)d_in[1];
    const int*   edst = (const int*)d_in[2];
    const float* ew   = (const float*)d_in[3];
    const float* W1   = (const float*)d_in[4];
    const float* b1   = (const float*)d_in[5];
    const float* W2   = (const float*)d_in[6];
    const float* b2   = (const float*)d_in[7];
    float* out = (float*)d_out;

    // workspace layout (~65 MB)
    char* p = (char*)d_ws;
    ushort_t* ahb = (ushort_t*)p;  p += (size_t)N_NODES * 64 * 2;   // 12.8M
    ushort_t* hb  = (ushort_t*)p;  p += (size_t)N_NODES * 64 * 2;   // 12.8M (ping-pong buf)
    ushort_t* zB  = (ushort_t*)p;  p += (size_t)N_NODES * 64 * 2;   // 12.8M
    int2*  csr     = (int2*)p;     p += (size_t)N_EDGES * 8;        // 25.6M
    int* cnt       = (int*)p;      p += (size_t)N_NODES * 4;
    int* pos       = (int*)p;      p += (size_t)N_NODES * 4;
    int* row_start = (int*)p;      p += (size_t)(N_NODES + 1) * 4;
    int* bsum      = (int*)p;      p += (size_t)SCAN_B * 4;
    int* boff      = (int*)p;      p += (size_t)SCAN_B * 4;

    const int EB = (N_EDGES + 255) / 256;

    hipLaunchKernelGGL(mlp_kernel, dim3(N_NODES / 32), dim3(256), 0, stream,
                       x, W1, b1, W2, b2, hb, ahb);

    // counting sort by dst, packed payload, then in-row sort by src
    hipLaunchKernelGGL(zero_cnt, dim3(SCAN_B), dim3(256), 0, stream, cnt);
    hipLaunchKernelGGL(count_keys, dim3(EB), dim3(256), 0, stream, edst, cnt);
    hipLaunchKernelGGL(scan_block_sums, dim3(SCAN_B), dim3(256), 0, stream, cnt, bsum);
    hipLaunchKernelGGL(scan_partials, dim3(1), dim3(512), 0, stream, bsum, boff);
    hipLaunchKernelGGL(scan_final, dim3(SCAN_B), dim3(256), 0, stream,
                       cnt, boff, row_start, pos);
    hipLaunchKernelGGL(fill_dst, dim3(EB), dim3(256), 0, stream,
                       esrc, edst, ew, pos, csr);
    hipLaunchKernelGGL(sort_rows, dim3(N_NODES / 4), dim3(256), 0, stream,
                       row_start, csr);

    // propagation: strict alternation. it even: ->zB, it odd: ->hb.
    // it=0: hb->zB; ... it=8: hb->zB; final (it=9): zB->out(fp32).
    const ushort_t* zi = hb;
    for (int it = 0; it < K_ITERS - 1; ++it) {
        ushort_t* zo = (it % 2 == 0) ? zB : hb;
        hipLaunchKernelGGL((spmm_kernel<false>), dim3(N_NODES / 4), dim3(256), 0, stream,
                           row_start, csr, zi, ahb, (void*)zo);
        zi = zo;
    }
    hipLaunchKernelGGL((spmm_kernel<true>), dim3(N_NODES / 4), dim3(256), 0, stream,
                       row_start, csr, zi, ahb, (void*)out);
}